// Round 10
// baseline (247.098 us; speedup 1.0000x reference)
//
#include <hip/hip_runtime.h>
#include <math.h>

typedef __attribute__((ext_vector_type(8))) __bf16 bf16x8;
typedef __attribute__((ext_vector_type(4))) __bf16 bf16x4;
typedef __attribute__((ext_vector_type(4))) short short4v;
typedef __attribute__((ext_vector_type(4))) float floatx4;
typedef __attribute__((ext_vector_type(8))) float floatx8;

__device__ __forceinline__ float fast_rcp(float x) { return __builtin_amdgcn_rcpf(x); }
__device__ __forceinline__ float sigmoidf_(float z) { return fast_rcp(1.0f + __expf(-z)); }
__device__ __forceinline__ float fast_tanh(float z) {
    float e = __expf(2.0f * z);
    return 1.0f - 2.0f * fast_rcp(e + 1.0f);
}
__device__ __forceinline__ float leaky(float v) { return fmaxf(v, 0.01f * v); }

// XOR-swizzled byte offset into a [row][128B] LDS tile (conflict-free b64/b128).
__device__ __forceinline__ int swzb(int row, int byteoff) {
    return row * 128 + (byteoff ^ ((row & 7) << 4));
}

// Dup-grid geometry: cell (y,x) = 128 B = 64 bf16 = G[y][x][0:32] ++ G[y][min(x+1,255)][0:32].
// tl/tr (and bl/br) of a bilinear fetch live in ONE 128B-aligned cache line:
// lines/point/grid drop 3 -> 2 (x0/x1 shared a line only for even x0 before),
// and the x1-clamp moves to build time (less VALU in the hot gather).
#define DUPELEMS (256 * 256 * 64)

// ---- build bf16 dup grids in workspace: 2 grids x 65536 cells x 8 chunks ----
__global__ void convert_grids_dup(const float* __restrict__ g0, const float* __restrict__ g1,
                                  __bf16* __restrict__ o0, __bf16* __restrict__ o1) {
    int j = blockIdx.x * blockDim.x + threadIdx.x;     // 2^20 threads
    int grid = j >> 19;
    int r = j & ((1 << 19) - 1);
    int cell = r >> 3;                                  // y*256+x
    int chunk = r & 7;                                  // 8 x 16B output chunks
    int y = cell >> 8, x = cell & 255;
    int xs = (chunk & 4) ? min(x + 1, 255) : x;         // x1 half clamps here
    const float* src = (grid ? g1 : g0) + (((y << 8) + xs) << 5) + (chunk & 3) * 8;
    __bf16* dst = (grid ? o1 : o0) + cell * 64 + chunk * 8;
    floatx8 v = *(const floatx8*)src;
    *(bf16x8*)dst = __builtin_convertvector(v, bf16x8);
}

// 64 points per wave; lane = point for encoder and fc3/fc4 epilogue.
// Blend is fragment-mapped (r3): lane (quad,l15) blends chunk `quad` of points
// {nt*16+l15} straight into its fc1 MFMA B-fragment -- X never touches LDS.
// fc2 consumes fc1's accumulators DIRECTLY (r4/r5). fc3/fc4 stay scalar (r6).
// Gather uses the r5 interleaved schedule with PLAIN loads (r8's C-level burst
// was sunk by the allocator; r9's asm-pinned burst regressed 127->144 by
// degrading scheduling/occupancy -- latency-exposure count is NOT the lever).
// NEW (r10): dup-grid addressing. tl/tr = one base + {0,+64B} immediate,
// bl/br likewise -> 2 lines/point/grid instead of 3, less address math.
// Discriminates request-rate-bound (expect ~95-110 us) vs L3-fill-bound
// (expect unchanged ~126-130 -> composed roofline).
// launch_bounds(256,3) -- NOT 4/5 (r4: tighter caps spill the 64-AGPR acc).
// W1/W2/biases stay in LDS (r1: global W loads added scattered-vmem slots).
template<bool BF16G>
__global__ __launch_bounds__(256, 3) void gridnet_fwd(
    const float2* __restrict__ pos, const float2* __restrict__ dir_,
    const float* __restrict__ pos_gridf, const float* __restrict__ dir_gridf,
    const __bf16* __restrict__ pos_gridb, const __bf16* __restrict__ dir_gridb,
    const float* __restrict__ enc_w1, const float* __restrict__ enc_b1,
    const float* __restrict__ enc_w2, const float* __restrict__ enc_b2,
    const float* __restrict__ fc_w1, const float* __restrict__ fc_b1,
    const float* __restrict__ fc_w2, const float* __restrict__ fc_b2,
    const float* __restrict__ fc_w3, const float* __restrict__ fc_b3,
    const float* __restrict__ fc_w4, const float* __restrict__ fc_b4,
    float* __restrict__ out, int n)
{
    // [0,8K) W1 swizzled [64 out][128B]; [8K,10K) W2 swizzled [16][128B]
    // [10K,30K) h2 scratch: wave w at 10K+w*5K, [64 pt][20 f32] (stride 80B)
    __shared__ __align__(1024) char smem[8192 + 2048 + 4 * 5120];
    __shared__ float b1lds[64];
    __shared__ float b2lds[16];

    const int tid  = threadIdx.x;
    const int lane = tid & 63;
    const int wid  = tid >> 6;
    const int quad = lane >> 4;
    const int l15  = lane & 15;

    char* W1p = smem;
    char* W2p = smem + 8192;
    float* H2f = (float*)(smem + 10240 + wid * 5120);

    for (int idx = tid; idx < 4096; idx += 256)
        *(__bf16*)(W1p + swzb(idx & 63, (idx >> 6) * 2)) = (__bf16)fc_w1[idx];
    for (int idx = tid; idx < 1024; idx += 256)
        *(__bf16*)(W2p + swzb(idx & 15, (idx >> 4) * 2)) = (__bf16)fc_w2[idx];
    if (tid < 64) b1lds[tid] = fc_b1[tid];
    if (tid < 16) b2lds[tid] = fc_b2[tid];
    __syncthreads();

    int i  = blockIdx.x * 256 + wid * 64 + lane;
    int ic = min(i, n - 1);

    // ---- encoders for both passes; coords packed for shfl distribution ----
    // pcp = x0 | y0<<8 | y1<<16 (x1 handled by the dup layout at build time)
    unsigned pcp[2];
    float xfp[2], yfp[2];
    #pragma unroll
    for (int pass = 0; pass < 2; ++pass) {
        float2 xy = pass ? dir_[ic] : pos[ic];
        float hh[4];
        #pragma unroll
        for (int k = 0; k < 4; ++k)
            hh[k] = fast_tanh(xy.x * enc_w1[k] + xy.y * enc_w1[4 + k] + enc_b1[k]);
        float e0 = enc_b2[0], e1 = enc_b2[1];
        #pragma unroll
        for (int k = 0; k < 4; ++k) {
            e0 += hh[k] * enc_w2[3 * k + 0];
            e1 += hh[k] * enc_w2[3 * k + 1];
        }
        float x = sigmoidf_(e0) * 255.0f;
        float y = sigmoidf_(e1) * 255.0f;
        int x0 = (int)x, y0 = (int)y;
        xfp[pass] = x - (float)x0;
        yfp[pass] = y - (float)y0;
        int y1 = min(y0 + 1, 255);
        pcp[pass] = (unsigned)x0 | ((unsigned)y0 << 8) | ((unsigned)y1 << 16);
    }

    // ---- gather + blend straight into fc1 B-fragments (registers) ----
    // xfr[ks][nt] = X[pt = nt*16+l15][feats ks*32 + quad*8 .. +7]
    bf16x8 xfr[2][4];
    #pragma unroll
    for (int ks = 0; ks < 2; ++ks) {
        #pragma unroll
        for (int nt = 0; nt < 4; ++nt) {
            const int src = nt * 16 + l15;
            unsigned pcq = (unsigned)__shfl((int)pcp[ks], src);
            float xfq = __shfl(xfp[ks], src);
            float yfq = __shfl(yfp[ks], src);
            int x0 = pcq & 255, y0 = (pcq >> 8) & 255, y1 = (pcq >> 16) & 255;
            float oxf = 1.0f - xfq, oyf = 1.0f - yfq;
            floatx8 r;
            if (BF16G) {
                const __bf16* ga = (ks ? dir_gridb : pos_gridb) + quad * 8;
                const __bf16* p0 = ga + (((y0 << 8) + x0) << 6);   // cell (y0,x0)
                const __bf16* p1 = ga + (((y1 << 8) + x0) << 6);   // cell (y1,x0)
                bf16x8 va = *(const bf16x8*)(p0);        // tl (x0 half)
                bf16x8 vb = *(const bf16x8*)(p0 + 32);   // tr (x1 half, same line)
                bf16x8 vc = *(const bf16x8*)(p1);        // bl
                bf16x8 vd = *(const bf16x8*)(p1 + 32);   // br
                r = (oyf * oxf) * __builtin_convertvector(va, floatx8)
                  + (oyf * xfq) * __builtin_convertvector(vb, floatx8)
                  + (yfq * oxf) * __builtin_convertvector(vc, floatx8)
                  + (yfq * xfq) * __builtin_convertvector(vd, floatx8);
            } else {
                int x1 = min(x0 + 1, 255);
                const float* ga = (ks ? dir_gridf : pos_gridf) + quad * 8;
                floatx8 va = *(const floatx8*)(ga + (((y0 << 8) + x0) << 5));
                floatx8 vb = *(const floatx8*)(ga + (((y0 << 8) + x1) << 5));
                floatx8 vc = *(const floatx8*)(ga + (((y1 << 8) + x0) << 5));
                floatx8 vd = *(const floatx8*)(ga + (((y1 << 8) + x1) << 5));
                r = (oyf * oxf) * va + (oyf * xfq) * vb + (yfq * oxf) * vc + (yfq * xfq) * vd;
            }
            xfr[ks][nt] = __builtin_convertvector(r, bf16x8);
        }
    }

    // ---- W1/W2 fragments + biases from LDS ----
    bf16x8 wf[2][4];
    #pragma unroll
    for (int ks = 0; ks < 2; ++ks)
        #pragma unroll
        for (int mt = 0; mt < 4; ++mt)
            wf[ks][mt] = *(const bf16x8*)(W1p + swzb(mt * 16 + l15, ks * 64 + quad * 16));
    // A-frag of 16x16x16: lane (quad,l15) holds W2[o=l15][f=kb*16+quad*4+j]
    short4v w2a[4];
    #pragma unroll
    for (int kb = 0; kb < 4; ++kb)
        w2a[kb] = *(const short4v*)(W2p + swzb(l15, kb * 32 + quad * 8));
    floatx4 b1v[4];
    #pragma unroll
    for (int mt = 0; mt < 4; ++mt)
        b1v[mt] = *(const floatx4*)(b1lds + mt * 16 + quad * 4);
    floatx4 b2v = *(const floatx4*)(b2lds + quad * 4);

    // ---- fc1: D[out 64][pt 64] = W1 * X^T : 32 MFMAs, all-register operands ----
    floatx4 acc[4][4];
    #pragma unroll
    for (int mt = 0; mt < 4; ++mt)
        #pragma unroll
        for (int nt = 0; nt < 4; ++nt)
            acc[mt][nt] = b1v[mt];
    #pragma unroll
    for (int ks = 0; ks < 2; ++ks)
        #pragma unroll
        for (int mt = 0; mt < 4; ++mt)
            #pragma unroll
            for (int nt = 0; nt < 4; ++nt)
                acc[mt][nt] = __builtin_amdgcn_mfma_f32_16x16x32_bf16(wf[ks][mt], xfr[ks][nt], acc[mt][nt], 0, 0, 0);

    // ---- fc2: D[out 16][pt 64], 16 K=16 MFMAs fed DIRECTLY from acc ----
    // fc1 D-layout == 16x16x16 B-fragment layout (k = quad*4+j, col = l15),
    // so bf16(leaky(acc[kb][nt])) is the fragment; no LDS, no exchange.
    floatx4 acc2[4];
    #pragma unroll
    for (int nt = 0; nt < 4; ++nt) acc2[nt] = b2v;
    #pragma unroll
    for (int kb = 0; kb < 4; ++kb) {
        #pragma unroll
        for (int nt = 0; nt < 4; ++nt) {
            bf16x4 hv;
            #pragma unroll
            for (int r = 0; r < 4; ++r)
                hv[r] = (__bf16)leaky(acc[kb][nt][r]);
            acc2[nt] = __builtin_amdgcn_mfma_f32_16x16x16bf16_1k(
                w2a[kb], __builtin_bit_cast(short4v, hv), acc2[nt], 0, 0, 0);
        }
    }

    // writeback h2 fp32: lane holds out-feats (quad*4..+3) of pt (nt*16+l15);
    // [64 pt][stride 20 f32] -> b128 stores, residues spread over banks.
    #pragma unroll
    for (int nt = 0; nt < 4; ++nt) {
        floatx4 hv;
        #pragma unroll
        for (int r = 0; r < 4; ++r)
            hv[r] = leaky(acc2[nt][r]);
        *(floatx4*)(H2f + (nt * 16 + l15) * 20 + quad * 4) = hv;
    }
    __asm__ volatile("s_waitcnt lgkmcnt(0)" ::: "memory");

    // ---- fc3/fc4 per lane (lane = point), sigmoid, store ----
    float h2[16];
    #pragma unroll
    for (int c = 0; c < 4; ++c) {
        floatx4 v = *(const floatx4*)(H2f + lane * 20 + c * 4);
        h2[4 * c + 0] = v[0]; h2[4 * c + 1] = v[1]; h2[4 * c + 2] = v[2]; h2[4 * c + 3] = v[3];
    }
    float h3[8];
    #pragma unroll
    for (int j = 0; j < 8; ++j) h3[j] = fc_b3[j];
    #pragma unroll
    for (int k = 0; k < 16; ++k) {
        float xv = h2[k];
        #pragma unroll
        for (int j = 0; j < 8; ++j) h3[j] = fmaf(xv, fc_w3[(k << 3) + j], h3[j]);
    }
    #pragma unroll
    for (int j = 0; j < 8; ++j) h3[j] = leaky(h3[j]);

    float o[3];
    #pragma unroll
    for (int j = 0; j < 3; ++j) o[j] = fc_b4[j];
    #pragma unroll
    for (int k = 0; k < 8; ++k) {
        float xv = h3[k];
        #pragma unroll
        for (int j = 0; j < 3; ++j) o[j] = fmaf(xv, fc_w4[3 * k + j], o[j]);
    }
    if (i < n) {
        #pragma unroll
        for (int j = 0; j < 3; ++j)
            out[3 * i + j] = sigmoidf_(leaky(o[j])) * 255.0f;
    }
}

extern "C" void kernel_launch(void* const* d_in, const int* in_sizes, int n_in,
                              void* d_out, int out_size, void* d_ws, size_t ws_size,
                              hipStream_t stream) {
    int n = in_sizes[0] / 2;  // pos is [N,2]
    bool use_bf16 = ws_size >= (size_t)(2 * DUPELEMS * sizeof(__bf16));  // 16 MB
    __bf16* g0 = (__bf16*)d_ws;
    __bf16* g1 = g0 + DUPELEMS;

    if (use_bf16) {
        int total = 2 * (DUPELEMS / 8);   // 16B chunks: 2 grids x 65536 cells x 8
        convert_grids_dup<<<(total + 255) / 256, 256, 0, stream>>>(
            (const float*)d_in[2], (const float*)d_in[3], g0, g1);
    }

    int blocks = (n + 255) / 256;
    if (use_bf16) {
        gridnet_fwd<true><<<blocks, 256, 0, stream>>>(
            (const float2*)d_in[0], (const float2*)d_in[1],
            (const float*)d_in[2], (const float*)d_in[3], g0, g1,
            (const float*)d_in[4], (const float*)d_in[5],
            (const float*)d_in[6], (const float*)d_in[7],
            (const float*)d_in[8], (const float*)d_in[9],
            (const float*)d_in[10], (const float*)d_in[11],
            (const float*)d_in[12], (const float*)d_in[13],
            (const float*)d_in[14], (const float*)d_in[15],
            (float*)d_out, n);
    } else {
        gridnet_fwd<false><<<blocks, 256, 0, stream>>>(
            (const float2*)d_in[0], (const float2*)d_in[1],
            (const float*)d_in[2], (const float*)d_in[3], g0, g1,
            (const float*)d_in[4], (const float*)d_in[5],
            (const float*)d_in[6], (const float*)d_in[7],
            (const float*)d_in[8], (const float*)d_in[9],
            (const float*)d_in[10], (const float*)d_in[11],
            (const float*)d_in[12], (const float*)d_in[13],
            (const float*)d_in[14], (const float*)d_in[15],
            (float*)d_out, n);
    }
}

// Round 12
// 218.184 us; speedup vs baseline: 1.1325x; 1.1325x over previous
//
#include <hip/hip_runtime.h>
#include <math.h>

typedef __attribute__((ext_vector_type(8))) __bf16 bf16x8;
typedef __attribute__((ext_vector_type(4))) __bf16 bf16x4;
typedef __attribute__((ext_vector_type(4))) short short4v;
typedef __attribute__((ext_vector_type(4))) float floatx4;
typedef __attribute__((ext_vector_type(8))) float floatx8;

__device__ __forceinline__ float fast_rcp(float x) { return __builtin_amdgcn_rcpf(x); }
__device__ __forceinline__ float sigmoidf_(float z) { return fast_rcp(1.0f + __expf(-z)); }
__device__ __forceinline__ float fast_tanh(float z) {
    float e = __expf(2.0f * z);
    return 1.0f - 2.0f * fast_rcp(e + 1.0f);
}
__device__ __forceinline__ float leaky(float v) { return fmaxf(v, 0.01f * v); }

// XOR-swizzled byte offset into a [row][128B] LDS tile (conflict-free b64/b128).
__device__ __forceinline__ int swzb(int row, int byteoff) {
    return row * 128 + (byteoff ^ ((row & 7) << 4));
}

// ---- grid fp32 -> bf16 conversion into workspace ----
__global__ void convert_grids(const float* __restrict__ g0, const float* __restrict__ g1,
                              __bf16* __restrict__ o0, __bf16* __restrict__ o1, int elems) {
    int i = blockIdx.x * blockDim.x + threadIdx.x;
    int nvec = elems >> 2;
    if (i < nvec) {
        float4 v = ((const float4*)g0)[i];
        bf16x4 r = { (__bf16)v.x, (__bf16)v.y, (__bf16)v.z, (__bf16)v.w };
        ((bf16x4*)o0)[i] = r;
    } else if (i < 2 * nvec) {
        int j = i - nvec;
        float4 v = ((const float4*)g1)[j];
        bf16x4 r = { (__bf16)v.x, (__bf16)v.y, (__bf16)v.z, (__bf16)v.w };
        ((bf16x4*)o1)[j] = r;
    }
}

// ============ r12 = r11 resubmit = r5 (best verified: main 126.5-127.9 us) ============
// Evidence ledger (r0-r10): the kernel sits at
//   dur ~= max(scattered-gather service floor ~125 us, VALU issue ~88 us)
// - gather floor invariant across schedules (r3 interleave / r8 soft-burst /
//   r9 asm-pinned burst), occupancy (r3 29% vs r5 40%), conflicts (8.5M->3.5M).
// - r10 dup-grid (footprint 8->16 MB): -28% -- L2-capacity bound confirmed;
//   compact bf16 grids (8 MB) are the optimal footprint. fp8 fails precision
//   arithmetic (e4m3 on N(0,10) -> O(10) output-unit error).
// Structure: 64 pts/wave; blend fragment-mapped into fc1 B-fragments (r3, no
// X LDS round-trip); fc2 fed directly from fc1 accumulators via the K=16 MFMA
// B-fragment identity (r4); fc3/fc4 scalar per lane (r6: MFMA-chaining the
// tail serializes); launch_bounds(256,3) (r4: tighter spills the 64-AGPR acc);
// W1/W2/biases in LDS (r1: global W loads added scattered-vmem slots).
template<bool BF16G>
__global__ __launch_bounds__(256, 3) void gridnet_fwd(
    const float2* __restrict__ pos, const float2* __restrict__ dir_,
    const float* __restrict__ pos_gridf, const float* __restrict__ dir_gridf,
    const __bf16* __restrict__ pos_gridb, const __bf16* __restrict__ dir_gridb,
    const float* __restrict__ enc_w1, const float* __restrict__ enc_b1,
    const float* __restrict__ enc_w2, const float* __restrict__ enc_b2,
    const float* __restrict__ fc_w1, const float* __restrict__ fc_b1,
    const float* __restrict__ fc_w2, const float* __restrict__ fc_b2,
    const float* __restrict__ fc_w3, const float* __restrict__ fc_b3,
    const float* __restrict__ fc_w4, const float* __restrict__ fc_b4,
    float* __restrict__ out, int n)
{
    // [0,8K) W1 swizzled [64 out][128B]; [8K,10K) W2 swizzled [16][128B]
    // [10K,30K) h2 scratch: wave w at 10K+w*5K, [64 pt][20 f32] (stride 80B)
    __shared__ __align__(1024) char smem[8192 + 2048 + 4 * 5120];
    __shared__ float b1lds[64];
    __shared__ float b2lds[16];

    const int tid  = threadIdx.x;
    const int lane = tid & 63;
    const int wid  = tid >> 6;
    const int quad = lane >> 4;
    const int l15  = lane & 15;

    char* W1p = smem;
    char* W2p = smem + 8192;
    float* H2f = (float*)(smem + 10240 + wid * 5120);

    for (int idx = tid; idx < 4096; idx += 256)
        *(__bf16*)(W1p + swzb(idx & 63, (idx >> 6) * 2)) = (__bf16)fc_w1[idx];
    for (int idx = tid; idx < 1024; idx += 256)
        *(__bf16*)(W2p + swzb(idx & 15, (idx >> 4) * 2)) = (__bf16)fc_w2[idx];
    if (tid < 64) b1lds[tid] = fc_b1[tid];
    if (tid < 16) b2lds[tid] = fc_b2[tid];
    __syncthreads();

    // hoisted: W1 A-fragments (K=32) + W2 A-fragments (K=16) + biases,
    // so the LDS pipe works while the gathers are in flight.
    bf16x8 wf[2][4];
    #pragma unroll
    for (int ks = 0; ks < 2; ++ks)
        #pragma unroll
        for (int mt = 0; mt < 4; ++mt)
            wf[ks][mt] = *(const bf16x8*)(W1p + swzb(mt * 16 + l15, ks * 64 + quad * 16));
    // A-frag of 16x16x16: lane (quad,l15) holds W2[o=l15][f=kb*16+quad*4+j]
    short4v w2a[4];
    #pragma unroll
    for (int kb = 0; kb < 4; ++kb)
        w2a[kb] = *(const short4v*)(W2p + swzb(l15, kb * 32 + quad * 8));
    floatx4 b1v[4];
    #pragma unroll
    for (int mt = 0; mt < 4; ++mt)
        b1v[mt] = *(const floatx4*)(b1lds + mt * 16 + quad * 4);
    floatx4 b2v = *(const floatx4*)(b2lds + quad * 4);

    int i  = blockIdx.x * 256 + wid * 64 + lane;
    int ic = min(i, n - 1);

    // ---- encoders for both passes; coords packed for shfl distribution ----
    unsigned pcp[2];
    float xfp[2], yfp[2];
    #pragma unroll
    for (int pass = 0; pass < 2; ++pass) {
        float2 xy = pass ? dir_[ic] : pos[ic];
        float hh[4];
        #pragma unroll
        for (int k = 0; k < 4; ++k)
            hh[k] = fast_tanh(xy.x * enc_w1[k] + xy.y * enc_w1[4 + k] + enc_b1[k]);
        float e0 = enc_b2[0], e1 = enc_b2[1];
        #pragma unroll
        for (int k = 0; k < 4; ++k) {
            e0 += hh[k] * enc_w2[3 * k + 0];
            e1 += hh[k] * enc_w2[3 * k + 1];
        }
        float x = sigmoidf_(e0) * 255.0f;
        float y = sigmoidf_(e1) * 255.0f;
        int x0 = (int)x, y0 = (int)y;
        xfp[pass] = x - (float)x0;
        yfp[pass] = y - (float)y0;
        int x1 = min(x0 + 1, 255), y1 = min(y0 + 1, 255);
        pcp[pass] = (unsigned)x0 | ((unsigned)y0 << 8) | ((unsigned)x1 << 16) | ((unsigned)y1 << 24);
    }

    // ---- gather + blend straight into fc1 B-fragments (registers) ----
    // xfr[ks][nt] = X[pt = nt*16+l15][feats ks*32 + quad*8 .. +7]
    bf16x8 xfr[2][4];
    #pragma unroll
    for (int ks = 0; ks < 2; ++ks) {
        #pragma unroll
        for (int nt = 0; nt < 4; ++nt) {
            const int src = nt * 16 + l15;
            unsigned pcq = (unsigned)__shfl((int)pcp[ks], src);
            float xfq = __shfl(xfp[ks], src);
            float yfq = __shfl(yfp[ks], src);
            int x0 = pcq & 255, y0 = (pcq >> 8) & 255;
            int x1 = (pcq >> 16) & 255, y1 = pcq >> 24;
            float oxf = 1.0f - xfq, oyf = 1.0f - yfq;
            floatx8 r;
            if (BF16G) {
                const __bf16* ga = (ks ? dir_gridb : pos_gridb) + quad * 8;
                bf16x8 va = *(const bf16x8*)(ga + (((y0 << 8) + x0) << 5));
                bf16x8 vb = *(const bf16x8*)(ga + (((y0 << 8) + x1) << 5));
                bf16x8 vc = *(const bf16x8*)(ga + (((y1 << 8) + x0) << 5));
                bf16x8 vd = *(const bf16x8*)(ga + (((y1 << 8) + x1) << 5));
                r = (oyf * oxf) * __builtin_convertvector(va, floatx8)
                  + (oyf * xfq) * __builtin_convertvector(vb, floatx8)
                  + (yfq * oxf) * __builtin_convertvector(vc, floatx8)
                  + (yfq * xfq) * __builtin_convertvector(vd, floatx8);
            } else {
                const float* ga = (ks ? dir_gridf : pos_gridf) + quad * 8;
                floatx8 va = *(const floatx8*)(ga + (((y0 << 8) + x0) << 5));
                floatx8 vb = *(const floatx8*)(ga + (((y0 << 8) + x1) << 5));
                floatx8 vc = *(const floatx8*)(ga + (((y1 << 8) + x0) << 5));
                floatx8 vd = *(const floatx8*)(ga + (((y1 << 8) + x1) << 5));
                r = (oyf * oxf) * va + (oyf * xfq) * vb + (yfq * oxf) * vc + (yfq * xfq) * vd;
            }
            xfr[ks][nt] = __builtin_convertvector(r, bf16x8);
        }
    }

    // ---- fc1: D[out 64][pt 64] = W1 * X^T : 32 MFMAs, all-register operands ----
    floatx4 acc[4][4];
    #pragma unroll
    for (int mt = 0; mt < 4; ++mt)
        #pragma unroll
        for (int nt = 0; nt < 4; ++nt)
            acc[mt][nt] = b1v[mt];
    #pragma unroll
    for (int ks = 0; ks < 2; ++ks)
        #pragma unroll
        for (int mt = 0; mt < 4; ++mt)
            #pragma unroll
            for (int nt = 0; nt < 4; ++nt)
                acc[mt][nt] = __builtin_amdgcn_mfma_f32_16x16x32_bf16(wf[ks][mt], xfr[ks][nt], acc[mt][nt], 0, 0, 0);

    // ---- fc2: D[out 16][pt 64], 16 K=16 MFMAs fed DIRECTLY from acc ----
    // fc1 D-layout == 16x16x16 B-fragment layout (k = quad*4+j, col = l15),
    // so bf16(leaky(acc[kb][nt])) is the fragment; no LDS, no exchange.
    floatx4 acc2[4];
    #pragma unroll
    for (int nt = 0; nt < 4; ++nt) acc2[nt] = b2v;
    #pragma unroll
    for (int kb = 0; kb < 4; ++kb) {
        #pragma unroll
        for (int nt = 0; nt < 4; ++nt) {
            bf16x4 hv;
            #pragma unroll
            for (int r = 0; r < 4; ++r)
                hv[r] = (__bf16)leaky(acc[kb][nt][r]);
            acc2[nt] = __builtin_amdgcn_mfma_f32_16x16x16bf16_1k(
                w2a[kb], __builtin_bit_cast(short4v, hv), acc2[nt], 0, 0, 0);
        }
    }

    // writeback h2 fp32: lane holds out-feats (quad*4..+3) of pt (nt*16+l15);
    // [64 pt][stride 20 f32] -> b128 stores, residues spread over banks.
    #pragma unroll
    for (int nt = 0; nt < 4; ++nt) {
        floatx4 hv;
        #pragma unroll
        for (int r = 0; r < 4; ++r)
            hv[r] = leaky(acc2[nt][r]);
        *(floatx4*)(H2f + (nt * 16 + l15) * 20 + quad * 4) = hv;
    }
    __asm__ volatile("s_waitcnt lgkmcnt(0)" ::: "memory");

    // ---- fc3/fc4 per lane (lane = point), sigmoid, store ----
    float h2[16];
    #pragma unroll
    for (int c = 0; c < 4; ++c) {
        floatx4 v = *(const floatx4*)(H2f + lane * 20 + c * 4);
        h2[4 * c + 0] = v[0]; h2[4 * c + 1] = v[1]; h2[4 * c + 2] = v[2]; h2[4 * c + 3] = v[3];
    }
    float h3[8];
    #pragma unroll
    for (int j = 0; j < 8; ++j) h3[j] = fc_b3[j];
    #pragma unroll
    for (int k = 0; k < 16; ++k) {
        float xv = h2[k];
        #pragma unroll
        for (int j = 0; j < 8; ++j) h3[j] = fmaf(xv, fc_w3[(k << 3) + j], h3[j]);
    }
    #pragma unroll
    for (int j = 0; j < 8; ++j) h3[j] = leaky(h3[j]);

    float o[3];
    #pragma unroll
    for (int j = 0; j < 3; ++j) o[j] = fc_b4[j];
    #pragma unroll
    for (int k = 0; k < 8; ++k) {
        float xv = h3[k];
        #pragma unroll
        for (int j = 0; j < 3; ++j) o[j] = fmaf(xv, fc_w4[3 * k + j], o[j]);
    }
    if (i < n) {
        #pragma unroll
        for (int j = 0; j < 3; ++j)
            out[3 * i + j] = sigmoidf_(leaky(o[j])) * 255.0f;
    }
}

extern "C" void kernel_launch(void* const* d_in, const int* in_sizes, int n_in,
                              void* d_out, int out_size, void* d_ws, size_t ws_size,
                              hipStream_t stream) {
    int n = in_sizes[0] / 2;  // pos is [N,2]
    const int GELEMS = 256 * 256 * 32;
    bool use_bf16 = ws_size >= (size_t)(2 * GELEMS * sizeof(__bf16));
    __bf16* g0 = (__bf16*)d_ws;
    __bf16* g1 = g0 + GELEMS;

    if (use_bf16) {
        int total = 2 * (GELEMS / 4);
        convert_grids<<<(total + 255) / 256, 256, 0, stream>>>(
            (const float*)d_in[2], (const float*)d_in[3], g0, g1, GELEMS);
    }

    int blocks = (n + 255) / 256;
    if (use_bf16) {
        gridnet_fwd<true><<<blocks, 256, 0, stream>>>(
            (const float2*)d_in[0], (const float2*)d_in[1],
            (const float*)d_in[2], (const float*)d_in[3], g0, g1,
            (const float*)d_in[4], (const float*)d_in[5],
            (const float*)d_in[6], (const float*)d_in[7],
            (const float*)d_in[8], (const float*)d_in[9],
            (const float*)d_in[10], (const float*)d_in[11],
            (const float*)d_in[12], (const float*)d_in[13],
            (const float*)d_in[14], (const float*)d_in[15],
            (float*)d_out, n);
    } else {
        gridnet_fwd<false><<<blocks, 256, 0, stream>>>(
            (const float2*)d_in[0], (const float2*)d_in[1],
            (const float*)d_in[2], (const float*)d_in[3], g0, g1,
            (const float*)d_in[4], (const float*)d_in[5],
            (const float*)d_in[6], (const float*)d_in[7],
            (const float*)d_in[8], (const float*)d_in[9],
            (const float*)d_in[10], (const float*)d_in[11],
            (const float*)d_in[12], (const float*)d_in[13],
            (const float*)d_in[14], (const float*)d_in[15],
            (float*)d_out, n);
    }
}